// Round 6
// baseline (3044.894 us; speedup 1.0000x reference)
//
#include <hip/hip_runtime.h>
#include <hip/hip_bf16.h>
#include <cstdint>

#define N_NODES 100000
#define N_EDGES 3200000
#define HID 256
#define NG 16
#define BN_EPS 1e-5f
#define B0 120      // bn0stats partial blocks
#define PB 128      // stats partial blocks

typedef unsigned short u16;
using bf16x8 = __attribute__((ext_vector_type(8))) short;
using f32x4  = __attribute__((ext_vector_type(4))) float;
using u16x4  = __attribute__((ext_vector_type(4))) unsigned short;

__device__ __forceinline__ float bf2f(u16 b) {
    return __uint_as_float(((unsigned)b) << 16);
}
__device__ __forceinline__ u16 f2bf(float f) {
    unsigned u = __float_as_uint(f);
    unsigned r = (u + 0x7FFFu + ((u >> 16) & 1u)) >> 16;
    return (u16)r;
}
__device__ __forceinline__ float4 ld_bf16x4(const u16* p) {
    ushort4 u = *reinterpret_cast<const ushort4*>(p);
    float4 f;
    f.x = bf2f(u.x); f.y = bf2f(u.y); f.z = bf2f(u.z); f.w = bf2f(u.w);
    return f;
}

// ---------------- CSR build ----------------
__global__ void k_count(const int* __restrict__ coli, int* __restrict__ cnt) {
    int i = blockIdx.x * blockDim.x + threadIdx.x;
    int st = gridDim.x * blockDim.x;
    for (; i < N_EDGES; i += st) atomicAdd(&cnt[__builtin_nontemporal_load(&coli[i])], 1);
}

__global__ void k_dinv(const int* __restrict__ cnt, float* __restrict__ dinv) {
    int i = blockIdx.x * blockDim.x + threadIdx.x;
    if (i < N_NODES) dinv[i] = rsqrtf((float)cnt[i] + 1.0f);
}

// 1024-thread single-block scan, wave-shuffle based
__global__ void k_scan(const int* __restrict__ cnt, int* __restrict__ ptr) {
    __shared__ int wsum[16];
    const int t = threadIdx.x;
    const int wv = t >> 6;
    const int ln = t & 63;
    int carry = 0;
    for (int base = 0; base < N_NODES; base += 4096) {
        int idx = base + t * 4;
        int v0 = 0, v1 = 0, v2 = 0, v3 = 0;
        if (idx + 3 < N_NODES) {
            int4 q = *reinterpret_cast<const int4*>(&cnt[idx]);
            v0 = q.x; v1 = q.y; v2 = q.z; v3 = q.w;
        } else {
            if (idx + 0 < N_NODES) v0 = cnt[idx + 0];
            if (idx + 1 < N_NODES) v1 = cnt[idx + 1];
            if (idx + 2 < N_NODES) v2 = cnt[idx + 2];
        }
        int s = v0 + v1 + v2 + v3;
        int sc = s;
        for (int off = 1; off < 64; off <<= 1) {
            int u = __shfl_up(sc, off);
            if (ln >= off) sc += u;
        }
        if (ln == 63) wsum[wv] = sc;
        __syncthreads();
        if (wv == 0 && ln < 16) {
            int a = wsum[ln];
            for (int off = 1; off < 16; off <<= 1) {
                int u = __shfl_up(a, off, 16);
                if (ln >= off) a += u;
            }
            wsum[ln] = a;
        }
        __syncthreads();
        int total = wsum[15];
        int excl = carry + (wv ? wsum[wv - 1] : 0) + sc - s;
        if (idx + 0 < N_NODES) ptr[idx + 0] = excl; excl += v0;
        if (idx + 1 < N_NODES) ptr[idx + 1] = excl; excl += v1;
        if (idx + 2 < N_NODES) ptr[idx + 2] = excl; excl += v2;
        if (idx + 3 < N_NODES) ptr[idx + 3] = excl;
        __syncthreads();
        carry += total;
    }
    if (t == 0) ptr[N_NODES] = carry;
}

__global__ void k_fill(const int* __restrict__ rowi, const int* __restrict__ coli,
                       const int* __restrict__ ptr, int* __restrict__ fc,
                       int* __restrict__ esrc) {
    int i = blockIdx.x * blockDim.x + threadIdx.x;
    int st = gridDim.x * blockDim.x;
    for (; i < N_EDGES; i += st) {
        int c = __builtin_nontemporal_load(&coli[i]);
        int r = __builtin_nontemporal_load(&rowi[i]);
        int p = ptr[c] + atomicAdd(&fc[c], 1);
        esrc[p] = r;
    }
}

// per-block LDS histogram -> 16 global atomics per block
__global__ __launch_bounds__(256) void k_batchcnt(const int* __restrict__ batch,
                                                  int* __restrict__ cg) {
    __shared__ int h[NG];
    if (threadIdx.x < NG) h[threadIdx.x] = 0;
    __syncthreads();
    int i = blockIdx.x * blockDim.x + threadIdx.x;
    if (i < N_NODES) atomicAdd(&h[batch[i]], 1);
    __syncthreads();
    if (threadIdx.x < NG) {
        int v = h[threadIdx.x];
        if (v) atomicAdd(&cg[threadIdx.x], v);
    }
}

// ---------------- BN0 stats: block-reduced partials ----------------
__global__ __launch_bounds__(256) void k_bn0stats(const float* __restrict__ pos,
                                                  const float* __restrict__ nrm,
                                                  float* __restrict__ part /* B0*12 */) {
    float s[6] = {0, 0, 0, 0, 0, 0}, q[6] = {0, 0, 0, 0, 0, 0};
    int i = blockIdx.x * blockDim.x + threadIdx.x;
    int stp = gridDim.x * blockDim.x;
    for (; i < N_NODES; i += stp) {
        float v;
        v = pos[i * 3 + 0]; s[0] += v; q[0] += v * v;
        v = pos[i * 3 + 1]; s[1] += v; q[1] += v * v;
        v = pos[i * 3 + 2]; s[2] += v; q[2] += v * v;
        v = nrm[i * 3 + 0]; s[3] += v; q[3] += v * v;
        v = nrm[i * 3 + 1]; s[4] += v; q[4] += v * v;
        v = nrm[i * 3 + 2]; s[5] += v; q[5] += v * v;
    }
#pragma unroll
    for (int k = 0; k < 6; ++k) {
        for (int o = 32; o > 0; o >>= 1) { s[k] += __shfl_down(s[k], o); q[k] += __shfl_down(q[k], o); }
    }
    __shared__ float ls[4][12];
    const int wv = threadIdx.x >> 6;
    const int ln = threadIdx.x & 63;
    if (ln == 0) {
#pragma unroll
        for (int k = 0; k < 6; ++k) { ls[wv][k] = s[k]; ls[wv][6 + k] = q[k]; }
    }
    __syncthreads();
    if (threadIdx.x < 12)
        part[blockIdx.x * 12 + threadIdx.x] =
            ls[0][threadIdx.x] + ls[1][threadIdx.x] + ls[2][threadIdx.x] + ls[3][threadIdx.x];
}

// ---------------- fold BN0 into W1 (K=6): Wf=A*W, rvB = B^T W ----------------
__global__ void k_fold6(const float* __restrict__ W,
                        const float* __restrict__ part, float invcnt,
                        const float* __restrict__ gamma, const float* __restrict__ beta,
                        float* __restrict__ Wf, float* __restrict__ rvB) {
    __shared__ float st[12];
    int c = threadIdx.x;
    if (c < 12) {
        float a = 0.f;
        for (int b = 0; b < B0; ++b) a += part[b * 12 + c];
        st[c] = a;
    }
    __syncthreads();
    float acc = 0.f;
    for (int k = 0; k < 6; ++k) {
        float m = st[k] * invcnt;
        float var = st[6 + k] * invcnt - m * m;
        float A = gamma[k] * rsqrtf(var + BN_EPS);
        float B = beta[k] - m * A;
        float w = W[k * HID + c];
        Wf[k * HID + c] = A * w;
        acc = fmaf(B, w, acc);
    }
    rvB[c] = acc;
}

// ---------------- fold for K=256 (reduces stats partials in preamble) ----------------
__global__ void k_fold256(const float* __restrict__ W,
                          const float* __restrict__ part /* PB*512 */, float invcnt,
                          const float* __restrict__ gamma, const float* __restrict__ beta,
                          u16* __restrict__ WhiT, u16* __restrict__ WloT,
                          float* __restrict__ rv) {
    __shared__ float ss[HID], sq[HID];
    int c = threadIdx.x;
    {
        float a = 0.f, b = 0.f;
#pragma unroll 4
        for (int bb = 0; bb < PB; ++bb) {
            a += part[bb * 512 + c];
            b += part[bb * 512 + HID + c];
        }
        ss[c] = a; sq[c] = b;
    }
    __syncthreads();
    float acc = 0.f;
    for (int k = 0; k < HID; ++k) {
        float m = ss[k] * invcnt;
        float var = sq[k] * invcnt - m * m;
        float A = gamma[k] * rsqrtf(var + BN_EPS);
        float B = beta[k] - m * A;
        float w = W[k * HID + c];
        float wf = A * w;
        u16 hi = f2bf(wf);
        WhiT[c * HID + k] = hi;
        WloT[c * HID + k] = f2bf(wf - bf2f(hi));
        acc = fmaf(B, w, acc);
    }
    rv[c] = acc;
}

// ---------------- layer-1 pre-aggregation in 6-dim raw space ----------------
__global__ __launch_bounds__(256) void k_agg6(
    const float* __restrict__ pos, const float* __restrict__ nrm,
    const int* __restrict__ ptr, const int* __restrict__ esrc,
    const float* __restrict__ dinv, float* __restrict__ z) {
    const int wv = threadIdx.x >> 6;
    const int ln = threadIdx.x & 63;
    const int n = blockIdx.x * 4 + wv;
    const float dn = dinv[n];
    float z0 = 0, z1 = 0, z2 = 0, z3 = 0, z4 = 0, z5 = 0, t = 0;
    const int s_ = ptr[n], e_ = ptr[n + 1];
    for (int e = s_ + ln; e < e_; e += 64) {
        int src = __builtin_nontemporal_load(&esrc[e]);
        float w = dn * dinv[src];
        z0 = fmaf(w, pos[src * 3 + 0], z0);
        z1 = fmaf(w, pos[src * 3 + 1], z1);
        z2 = fmaf(w, pos[src * 3 + 2], z2);
        z3 = fmaf(w, nrm[src * 3 + 0], z3);
        z4 = fmaf(w, nrm[src * 3 + 1], z4);
        z5 = fmaf(w, nrm[src * 3 + 2], z5);
        t += w;
    }
    if (ln == 0) {   // self loop
        float sl = dn * dn;
        z0 = fmaf(sl, pos[n * 3 + 0], z0);
        z1 = fmaf(sl, pos[n * 3 + 1], z1);
        z2 = fmaf(sl, pos[n * 3 + 2], z2);
        z3 = fmaf(sl, nrm[n * 3 + 0], z3);
        z4 = fmaf(sl, nrm[n * 3 + 1], z4);
        z5 = fmaf(sl, nrm[n * 3 + 2], z5);
        t += sl;
    }
#pragma unroll
    for (int o = 1; o < 64; o <<= 1) {
        z0 += __shfl_xor(z0, o); z1 += __shfl_xor(z1, o); z2 += __shfl_xor(z2, o);
        z3 += __shfl_xor(z3, o); z4 += __shfl_xor(z4, o); z5 += __shfl_xor(z5, o);
        t  += __shfl_xor(t, o);
    }
    if (ln == 0) {
        f32x4 a = {z0, z1, z2, z3};
        f32x4 b = {z4, z5, t, 0.f};
        __builtin_nontemporal_store(a, reinterpret_cast<f32x4*>(&z[n * 8]));
        __builtin_nontemporal_store(b, reinterpret_cast<f32x4*>(&z[n * 8 + 4]));
    }
}

// ---------------- layer-1: y1 = relu(z6 @ Wf + s*rvB + b1) -> bf16 ----------------
__global__ __launch_bounds__(256) void k_gemm1b(
    const float* __restrict__ z, const float* __restrict__ Wf,
    const float* __restrict__ rvB, const float* __restrict__ b1,
    u16* __restrict__ out) {
    const int c = threadIdx.x;
    float w0 = Wf[0 * HID + c], w1 = Wf[1 * HID + c], w2 = Wf[2 * HID + c];
    float w3 = Wf[3 * HID + c], w4 = Wf[4 * HID + c], w5 = Wf[5 * HID + c];
    const float rvc = rvB[c], bc = b1[c];
    for (int n = blockIdx.x; n < N_NODES; n += gridDim.x) {
        float x0 = z[n * 8 + 0], x1 = z[n * 8 + 1], x2 = z[n * 8 + 2];
        float x3 = z[n * 8 + 3], x4 = z[n * 8 + 4], x5 = z[n * 8 + 5];
        float s  = z[n * 8 + 6];
        float acc = fmaf(s, rvc, bc);
        acc = fmaf(x0, w0, acc); acc = fmaf(x1, w1, acc); acc = fmaf(x2, w2, acc);
        acc = fmaf(x3, w3, acc); acc = fmaf(x4, w4, acc); acc = fmaf(x5, w5, acc);
        __builtin_nontemporal_store(f2bf(fmaxf(acc, 0.f)), &out[(size_t)n * HID + c]);
    }
}

// ---------------- MFMA GEMM: [N,256](bf16) @ (WhiT+WloT) + rv -> bf16 ----------------
__global__ __launch_bounds__(256) void k_gemm_mfma(
    const u16* __restrict__ X, const u16* __restrict__ WhiT,
    const u16* __restrict__ WloT, const float* __restrict__ rv,
    u16* __restrict__ out) {
    const int tid = threadIdx.x;
    const int wv = tid >> 6;
    const int ln = tid & 63;
    const int row0 = blockIdx.x * 64;
    const int lr = ln & 15;
    const int lk = (ln >> 4) * 8;
    const int wcol0 = wv * 64;

    f32x4 acc[4][4] = {};
    for (int kk = 0; kk < HID; kk += 32) {
        bf16x8 a[4], bh[4], bl[4];
#pragma unroll
        for (int i = 0; i < 4; ++i) {
            int r = row0 + i * 16 + lr;
            if (r >= N_NODES) r = N_NODES - 1;
            a[i] = *reinterpret_cast<const bf16x8*>(&X[(size_t)r * HID + kk + lk]);
        }
#pragma unroll
        for (int c = 0; c < 4; ++c) {
            int col = wcol0 + c * 16 + lr;
            bh[c] = *reinterpret_cast<const bf16x8*>(&WhiT[(size_t)col * HID + kk + lk]);
            bl[c] = *reinterpret_cast<const bf16x8*>(&WloT[(size_t)col * HID + kk + lk]);
        }
#pragma unroll
        for (int i = 0; i < 4; ++i)
#pragma unroll
            for (int c = 0; c < 4; ++c) {
                acc[i][c] = __builtin_amdgcn_mfma_f32_16x16x32_bf16(a[i], bh[c], acc[i][c], 0, 0, 0);
                acc[i][c] = __builtin_amdgcn_mfma_f32_16x16x32_bf16(a[i], bl[c], acc[i][c], 0, 0, 0);
            }
    }
    const int crow = (ln >> 4) * 4;
#pragma unroll
    for (int c = 0; c < 4; ++c) {
        int col = wcol0 + c * 16 + lr;
        float rvc = rv[col];
#pragma unroll
        for (int i = 0; i < 4; ++i) {
#pragma unroll
            for (int rg = 0; rg < 4; ++rg) {
                int r = row0 + i * 16 + crow + rg;
                if (r < N_NODES)
                    out[(size_t)r * HID + col] = f2bf(acc[i][c][rg] + rvc);
            }
        }
    }
}

// ---------------- aggregation: y = relu(S.xw + bias) ----------------
__global__ __launch_bounds__(256) void k_agg(
    const u16* __restrict__ xw, const int* __restrict__ ptr,
    const int* __restrict__ esrc, const float* __restrict__ dinv,
    const float* __restrict__ bias, u16* __restrict__ y) {
    const int wv = threadIdx.x >> 6;
    const int ln = threadIdx.x & 63;
    const int n = blockIdx.x * 4 + wv;
    const float dn = dinv[n];
    const size_t base = (size_t)n * HID + ln * 4;
    float4 v = ld_bf16x4(&xw[base]);
    const float sl = dn * dn;
    float a0 = v.x * sl, a1 = v.y * sl, a2 = v.z * sl, a3 = v.w * sl;
    const int s = ptr[n], e = ptr[n + 1];
#pragma unroll 2
    for (int i = s; i < e; ++i) {
        int src = __builtin_nontemporal_load(&esrc[i]);
        float w = dinv[src] * dn;
        float4 u = ld_bf16x4(&xw[(size_t)src * HID + ln * 4]);
        a0 = fmaf(w, u.x, a0);
        a1 = fmaf(w, u.y, a1);
        a2 = fmaf(w, u.z, a2);
        a3 = fmaf(w, u.w, a3);
    }
    float4 b = *reinterpret_cast<const float4*>(&bias[ln * 4]);
    a0 = fmaxf(a0 + b.x, 0.f);
    a1 = fmaxf(a1 + b.y, 0.f);
    a2 = fmaxf(a2 + b.z, 0.f);
    a3 = fmaxf(a3 + b.w, 0.f);
    u16x4 o = {f2bf(a0), f2bf(a1), f2bf(a2), f2bf(a3)};
    __builtin_nontemporal_store(o, reinterpret_cast<u16x4*>(&y[base]));
}

// ---------------- per-channel stats partials (no atomics, NT, 4x ILP) ----------------
__global__ __launch_bounds__(256) void k_stats(const u16* __restrict__ y,
                                               float* __restrict__ part /* PB*512 */) {
    const int c = threadIdx.x;
    float s = 0.f, q = 0.f;
    for (int n = blockIdx.x; n < N_NODES; n += PB * 4) {
        int n1 = n + PB, n2 = n + PB * 2, n3 = n + PB * 3;
        float v0 = bf2f(__builtin_nontemporal_load(&y[(size_t)n * HID + c]));
        float v1 = (n1 < N_NODES) ? bf2f(__builtin_nontemporal_load(&y[(size_t)n1 * HID + c])) : 0.f;
        float v2 = (n2 < N_NODES) ? bf2f(__builtin_nontemporal_load(&y[(size_t)n2 * HID + c])) : 0.f;
        float v3 = (n3 < N_NODES) ? bf2f(__builtin_nontemporal_load(&y[(size_t)n3 * HID + c])) : 0.f;
        s += v0 + v1 + v2 + v3;
        q = fmaf(v0, v0, q); q = fmaf(v1, v1, q);
        q = fmaf(v2, v2, q); q = fmaf(v3, v3, q);
    }
    part[blockIdx.x * 512 + c] = s;
    part[blockIdx.x * 512 + HID + c] = q;
}

// ---------------- pooled sums by graph (batch is sorted) ----------------
__global__ __launch_bounds__(256) void k_pool(
    const u16* __restrict__ y, const int* __restrict__ batch,
    float* __restrict__ ps) {
    const int c = threadIdx.x;
    int r0 = blockIdx.x * 64;
    if (r0 >= N_NODES) return;
    int rend = (r0 + 64 < N_NODES) ? r0 + 64 : N_NODES;
    int cur = batch[r0];
    float acc = 0.f;
    for (int r = r0; r < rend; ++r) {
        int g = batch[r];
        if (g != cur) {
            atomicAdd(&ps[cur * HID + c], acc);
            acc = 0.f;
            cur = g;
        }
        acc += bf2f(y[(size_t)r * HID + c]);
    }
    atomicAdd(&ps[cur * HID + c], acc);
}

// ---------------- finalize: BN4 affine on pooled sums (reduces partials) ----------------
__global__ void k_final(const float* __restrict__ ps, const int* __restrict__ cg,
                        const float* __restrict__ part, const float* __restrict__ gamma,
                        const float* __restrict__ beta, float* __restrict__ out) {
    __shared__ float ss[HID], sq[HID];
    const int c = threadIdx.x;
    {
        float a = 0.f, b = 0.f;
#pragma unroll 4
        for (int bb = 0; bb < PB; ++bb) {
            a += part[bb * 512 + c];
            b += part[bb * 512 + HID + c];
        }
        ss[c] = a; sq[c] = b;
    }
    __syncthreads();
    const float invn = 1.0f / (float)N_NODES;
    float m = ss[c] * invn;
    float var = sq[c] * invn - m * m;
    float A = gamma[c] * rsqrtf(var + BN_EPS);
    float B = beta[c] - m * A;
    for (int g = 0; g < NG; ++g) {
        float cn = (float)cg[g];
        float val = (A * ps[g * HID + c] + cn * B) / fmaxf(cn, 1.0f);
        out[g * HID + c] = val;
    }
}

extern "C" void kernel_launch(void* const* d_in, const int* in_sizes, int n_in,
                              void* d_out, int out_size, void* d_ws, size_t ws_size,
                              hipStream_t stream) {
    const float* pos   = (const float*)d_in[0];
    const float* nrm   = (const float*)d_in[1];
    const int*   ei    = (const int*)d_in[2];
    const int*   batch = (const int*)d_in[3];
    const float* bn0g  = (const float*)d_in[4];
    const float* bn0b  = (const float*)d_in[5];
    const float* W[4]   = {(const float*)d_in[6],  (const float*)d_in[10], (const float*)d_in[14], (const float*)d_in[18]};
    const float* bb[4]  = {(const float*)d_in[7],  (const float*)d_in[11], (const float*)d_in[15], (const float*)d_in[19]};
    const float* bg[4]  = {(const float*)d_in[8],  (const float*)d_in[12], (const float*)d_in[16], (const float*)d_in[20]};
    const float* bbt[4] = {(const float*)d_in[9],  (const float*)d_in[13], (const float*)d_in[17], (const float*)d_in[21]};

    char* wp = (char*)d_ws;
    auto alloc = [&](size_t bytes) {
        char* p = wp;
        wp += (bytes + 255) & ~(size_t)255;
        return p;
    };
    float* dinv  = (float*)alloc((size_t)N_NODES * 4);
    int*   cnt   = (int*)  alloc((size_t)N_NODES * 4);
    int*   ptr   = (int*)  alloc((size_t)(N_NODES + 1) * 4);
    int*   esrc  = (int*)  alloc((size_t)N_EDGES * 4);
    u16*   bufA  = (u16*)  alloc((size_t)N_NODES * HID * 2);
    u16*   bufB  = (u16*)  alloc((size_t)N_NODES * HID * 2);
    float* zbuf  = (float*)alloc((size_t)N_NODES * 8 * 4);
    float* part0 = (float*)alloc((size_t)B0 * 12 * 4);
    float* partL = (float*)alloc((size_t)PB * 512 * 4);
    float* Wf1   = (float*)alloc((size_t)6 * HID * 4);
    u16*   WhiT  = (u16*)  alloc((size_t)HID * HID * 2);
    u16*   WloT  = (u16*)  alloc((size_t)HID * HID * 2);
    float* rv    = (float*)alloc(HID * 4);
    float* ps    = (float*)alloc(NG * HID * 4);
    int*   cg    = (int*)  alloc(NG * 4);
    (void)ws_size; (void)in_sizes; (void)n_in; (void)out_size;

    const int* rowi = ei;
    const int* coli = ei + N_EDGES;

    hipMemsetAsync(cnt, 0, (size_t)N_NODES * 4, stream);
    hipMemsetAsync(ps, 0, NG * HID * 4, stream);
    hipMemsetAsync(cg, 0, NG * 4, stream);

    // CSR + norms
    k_count<<<2048, 256, 0, stream>>>(coli, cnt);
    k_dinv<<<(N_NODES + 255) / 256, 256, 0, stream>>>(cnt, dinv);
    k_scan<<<1, 1024, 0, stream>>>(cnt, ptr);
    hipMemsetAsync(cnt, 0, (size_t)N_NODES * 4, stream);
    k_fill<<<2048, 256, 0, stream>>>(rowi, coli, ptr, cnt, esrc);
    k_batchcnt<<<(N_NODES + 255) / 256, 256, 0, stream>>>(batch, cg);

    // layer 1: aggregate in 6-dim raw space, then tiny GEMM with BN0 folded
    k_bn0stats<<<B0, 256, 0, stream>>>(pos, nrm, part0);
    k_fold6<<<1, 256, 0, stream>>>(W[0], part0, 1.0f / (float)N_NODES, bn0g, bn0b, Wf1, rv);
    k_agg6<<<N_NODES / 4, 256, 0, stream>>>(pos, nrm, ptr, esrc, dinv, zbuf);
    k_gemm1b<<<2048, 256, 0, stream>>>(zbuf, Wf1, rv, bb[0], bufA);   // bufA = a_1

    // layers 2..4: stats -> fold BN_l into W_{l+1} -> MFMA gemm -> aggregate
    for (int l = 0; l < 3; ++l) {
        k_stats<<<PB, 256, 0, stream>>>(bufA, partL);
        k_fold256<<<1, 256, 0, stream>>>(W[l + 1], partL, 1.0f / (float)N_NODES,
                                         bg[l], bbt[l], WhiT, WloT, rv);
        k_gemm_mfma<<<(N_NODES + 63) / 64, 256, 0, stream>>>(bufA, WhiT, WloT, rv, bufB);
        k_agg<<<N_NODES / 4, 256, 0, stream>>>(bufB, ptr, esrc, dinv, bb[l + 1], bufA);
    }

    // final BN4 applied analytically on pooled sums
    k_stats<<<PB, 256, 0, stream>>>(bufA, partL);
    k_pool<<<(N_NODES + 63) / 64, 256, 0, stream>>>(bufA, batch, ps);
    k_final<<<1, 256, 0, stream>>>(ps, cg, partL, bg[3], bbt[3], (float*)d_out);
}

// Round 7
// 2138.998 us; speedup vs baseline: 1.4235x; 1.4235x over previous
//
#include <hip/hip_runtime.h>
#include <hip/hip_bf16.h>
#include <cstdint>

#define N_NODES 100000
#define N_EDGES 3200000
#define HID 256
#define NG 16
#define BN_EPS 1e-5f
#define B0 120       // bn0stats partial blocks
#define PB 1024      // stats partial blocks
#define SROWS ((N_NODES + PB - 1) / PB)   // 98 rows per stats block

typedef unsigned short u16;
using bf16x8 = __attribute__((ext_vector_type(8))) short;
using f32x4  = __attribute__((ext_vector_type(4))) float;
using u16x4  = __attribute__((ext_vector_type(4))) unsigned short;

__device__ __forceinline__ float bf2f(u16 b) {
    return __uint_as_float(((unsigned)b) << 16);
}
__device__ __forceinline__ u16 f2bf(float f) {
    unsigned u = __float_as_uint(f);
    unsigned r = (u + 0x7FFFu + ((u >> 16) & 1u)) >> 16;
    return (u16)r;
}
__device__ __forceinline__ float4 ld_bf16x4(const u16* p) {
    ushort4 u = *reinterpret_cast<const ushort4*>(p);
    float4 f;
    f.x = bf2f(u.x); f.y = bf2f(u.y); f.z = bf2f(u.z); f.w = bf2f(u.w);
    return f;
}

// ---------------- CSR build ----------------
__global__ void k_count(const int* __restrict__ coli, int* __restrict__ cnt) {
    int i = blockIdx.x * blockDim.x + threadIdx.x;
    int st = gridDim.x * blockDim.x;
    for (; i < N_EDGES; i += st) atomicAdd(&cnt[__builtin_nontemporal_load(&coli[i])], 1);
}

__global__ void k_dinv(const int* __restrict__ cnt, float* __restrict__ dinv) {
    int i = blockIdx.x * blockDim.x + threadIdx.x;
    if (i < N_NODES) dinv[i] = rsqrtf((float)cnt[i] + 1.0f);
}

// 1024-thread single-block scan, wave-shuffle based
__global__ void k_scan(const int* __restrict__ cnt, int* __restrict__ ptr) {
    __shared__ int wsum[16];
    const int t = threadIdx.x;
    const int wv = t >> 6;
    const int ln = t & 63;
    int carry = 0;
    for (int base = 0; base < N_NODES; base += 4096) {
        int idx = base + t * 4;
        int v0 = 0, v1 = 0, v2 = 0, v3 = 0;
        if (idx + 3 < N_NODES) {
            int4 q = *reinterpret_cast<const int4*>(&cnt[idx]);
            v0 = q.x; v1 = q.y; v2 = q.z; v3 = q.w;
        } else {
            if (idx + 0 < N_NODES) v0 = cnt[idx + 0];
            if (idx + 1 < N_NODES) v1 = cnt[idx + 1];
            if (idx + 2 < N_NODES) v2 = cnt[idx + 2];
        }
        int s = v0 + v1 + v2 + v3;
        int sc = s;
        for (int off = 1; off < 64; off <<= 1) {
            int u = __shfl_up(sc, off);
            if (ln >= off) sc += u;
        }
        if (ln == 63) wsum[wv] = sc;
        __syncthreads();
        if (wv == 0 && ln < 16) {
            int a = wsum[ln];
            for (int off = 1; off < 16; off <<= 1) {
                int u = __shfl_up(a, off, 16);
                if (ln >= off) a += u;
            }
            wsum[ln] = a;
        }
        __syncthreads();
        int total = wsum[15];
        int excl = carry + (wv ? wsum[wv - 1] : 0) + sc - s;
        if (idx + 0 < N_NODES) ptr[idx + 0] = excl; excl += v0;
        if (idx + 1 < N_NODES) ptr[idx + 1] = excl; excl += v1;
        if (idx + 2 < N_NODES) ptr[idx + 2] = excl; excl += v2;
        if (idx + 3 < N_NODES) ptr[idx + 3] = excl;
        __syncthreads();
        carry += total;
    }
    if (t == 0) ptr[N_NODES] = carry;
}

__global__ void k_fill(const int* __restrict__ rowi, const int* __restrict__ coli,
                       const int* __restrict__ ptr, int* __restrict__ fc,
                       int* __restrict__ esrc) {
    int i = blockIdx.x * blockDim.x + threadIdx.x;
    int st = gridDim.x * blockDim.x;
    for (; i < N_EDGES; i += st) {
        int c = __builtin_nontemporal_load(&coli[i]);
        int r = __builtin_nontemporal_load(&rowi[i]);
        int p = ptr[c] + atomicAdd(&fc[c], 1);
        esrc[p] = r;
    }
}

// per-block LDS histogram -> 16 global atomics per block
__global__ __launch_bounds__(256) void k_batchcnt(const int* __restrict__ batch,
                                                  int* __restrict__ cg) {
    __shared__ int h[NG];
    if (threadIdx.x < NG) h[threadIdx.x] = 0;
    __syncthreads();
    int i = blockIdx.x * blockDim.x + threadIdx.x;
    if (i < N_NODES) atomicAdd(&h[batch[i]], 1);
    __syncthreads();
    if (threadIdx.x < NG) {
        int v = h[threadIdx.x];
        if (v) atomicAdd(&cg[threadIdx.x], v);
    }
}

// ---------------- BN0 stats: block-reduced partials ----------------
__global__ __launch_bounds__(256) void k_bn0stats(const float* __restrict__ pos,
                                                  const float* __restrict__ nrm,
                                                  float* __restrict__ part /* B0*12 */) {
    float s[6] = {0, 0, 0, 0, 0, 0}, q[6] = {0, 0, 0, 0, 0, 0};
    int i = blockIdx.x * blockDim.x + threadIdx.x;
    int stp = gridDim.x * blockDim.x;
    for (; i < N_NODES; i += stp) {
        float v;
        v = pos[i * 3 + 0]; s[0] += v; q[0] += v * v;
        v = pos[i * 3 + 1]; s[1] += v; q[1] += v * v;
        v = pos[i * 3 + 2]; s[2] += v; q[2] += v * v;
        v = nrm[i * 3 + 0]; s[3] += v; q[3] += v * v;
        v = nrm[i * 3 + 1]; s[4] += v; q[4] += v * v;
        v = nrm[i * 3 + 2]; s[5] += v; q[5] += v * v;
    }
#pragma unroll
    for (int k = 0; k < 6; ++k) {
        for (int o = 32; o > 0; o >>= 1) { s[k] += __shfl_down(s[k], o); q[k] += __shfl_down(q[k], o); }
    }
    __shared__ float ls[4][12];
    const int wv = threadIdx.x >> 6;
    const int ln = threadIdx.x & 63;
    if (ln == 0) {
#pragma unroll
        for (int k = 0; k < 6; ++k) { ls[wv][k] = s[k]; ls[wv][6 + k] = q[k]; }
    }
    __syncthreads();
    if (threadIdx.x < 12)
        part[blockIdx.x * 12 + threadIdx.x] =
            ls[0][threadIdx.x] + ls[1][threadIdx.x] + ls[2][threadIdx.x] + ls[3][threadIdx.x];
}

// ---------------- fold BN0 into W1 (K=6): Wf=A*W, rvB = B^T W ----------------
__global__ void k_fold6(const float* __restrict__ W,
                        const float* __restrict__ part, float invcnt,
                        const float* __restrict__ gamma, const float* __restrict__ beta,
                        float* __restrict__ Wf, float* __restrict__ rvB) {
    __shared__ float st[12];
    int c = threadIdx.x;
    if (c < 12) {
        float a = 0.f;
        for (int b = 0; b < B0; ++b) a += part[b * 12 + c];
        st[c] = a;
    }
    __syncthreads();
    float acc = 0.f;
    for (int k = 0; k < 6; ++k) {
        float m = st[k] * invcnt;
        float var = st[6 + k] * invcnt - m * m;
        float A = gamma[k] * rsqrtf(var + BN_EPS);
        float B = beta[k] - m * A;
        float w = W[k * HID + c];
        Wf[k * HID + c] = A * w;
        acc = fmaf(B, w, acc);
    }
    rvB[c] = acc;
}

// ---------------- fold for K=256 (reduces stats partials in preamble) ----------------
__global__ void k_fold256(const float* __restrict__ W,
                          const float* __restrict__ part /* PB*512 */, float invcnt,
                          const float* __restrict__ gamma, const float* __restrict__ beta,
                          u16* __restrict__ WhiT, u16* __restrict__ WloT,
                          float* __restrict__ rv) {
    __shared__ float ss[HID], sq[HID];
    int c = threadIdx.x;
    {
        float a = 0.f, b = 0.f;
#pragma unroll 4
        for (int bb = 0; bb < PB; ++bb) {
            a += part[bb * 512 + c];
            b += part[bb * 512 + HID + c];
        }
        ss[c] = a; sq[c] = b;
    }
    __syncthreads();
    float acc = 0.f;
    for (int k = 0; k < HID; ++k) {
        float m = ss[k] * invcnt;
        float var = sq[k] * invcnt - m * m;
        float A = gamma[k] * rsqrtf(var + BN_EPS);
        float B = beta[k] - m * A;
        float w = W[k * HID + c];
        float wf = A * w;
        u16 hi = f2bf(wf);
        WhiT[c * HID + k] = hi;
        WloT[c * HID + k] = f2bf(wf - bf2f(hi));
        acc = fmaf(B, w, acc);
    }
    rv[c] = acc;
}

// ---------------- layer-1 pre-aggregation in 6-dim raw space ----------------
__global__ __launch_bounds__(256) void k_agg6(
    const float* __restrict__ pos, const float* __restrict__ nrm,
    const int* __restrict__ ptr, const int* __restrict__ esrc,
    const float* __restrict__ dinv, float* __restrict__ z) {
    const int wv = threadIdx.x >> 6;
    const int ln = threadIdx.x & 63;
    const int n = blockIdx.x * 4 + wv;
    const float dn = dinv[n];
    float z0 = 0, z1 = 0, z2 = 0, z3 = 0, z4 = 0, z5 = 0, t = 0;
    const int s_ = ptr[n], e_ = ptr[n + 1];
    for (int e = s_ + ln; e < e_; e += 64) {
        int src = __builtin_nontemporal_load(&esrc[e]);
        float w = dn * dinv[src];
        z0 = fmaf(w, pos[src * 3 + 0], z0);
        z1 = fmaf(w, pos[src * 3 + 1], z1);
        z2 = fmaf(w, pos[src * 3 + 2], z2);
        z3 = fmaf(w, nrm[src * 3 + 0], z3);
        z4 = fmaf(w, nrm[src * 3 + 1], z4);
        z5 = fmaf(w, nrm[src * 3 + 2], z5);
        t += w;
    }
    if (ln == 0) {   // self loop
        float sl = dn * dn;
        z0 = fmaf(sl, pos[n * 3 + 0], z0);
        z1 = fmaf(sl, pos[n * 3 + 1], z1);
        z2 = fmaf(sl, pos[n * 3 + 2], z2);
        z3 = fmaf(sl, nrm[n * 3 + 0], z3);
        z4 = fmaf(sl, nrm[n * 3 + 1], z4);
        z5 = fmaf(sl, nrm[n * 3 + 2], z5);
        t += sl;
    }
#pragma unroll
    for (int o = 1; o < 64; o <<= 1) {
        z0 += __shfl_xor(z0, o); z1 += __shfl_xor(z1, o); z2 += __shfl_xor(z2, o);
        z3 += __shfl_xor(z3, o); z4 += __shfl_xor(z4, o); z5 += __shfl_xor(z5, o);
        t  += __shfl_xor(t, o);
    }
    if (ln == 0) {
        *reinterpret_cast<f32x4*>(&z[n * 8])     = f32x4{z0, z1, z2, z3};
        *reinterpret_cast<f32x4*>(&z[n * 8 + 4]) = f32x4{z4, z5, t, 0.f};
    }
}

// ---------------- layer-1: y1 = relu(z6 @ Wf + s*rvB + b1) -> bf16 ----------------
__global__ __launch_bounds__(256) void k_gemm1b(
    const float* __restrict__ z, const float* __restrict__ Wf,
    const float* __restrict__ rvB, const float* __restrict__ b1,
    u16* __restrict__ out) {
    const int c = threadIdx.x;
    float w0 = Wf[0 * HID + c], w1 = Wf[1 * HID + c], w2 = Wf[2 * HID + c];
    float w3 = Wf[3 * HID + c], w4 = Wf[4 * HID + c], w5 = Wf[5 * HID + c];
    const float rvc = rvB[c], bc = b1[c];
    for (int n = blockIdx.x; n < N_NODES; n += gridDim.x) {
        float x0 = z[n * 8 + 0], x1 = z[n * 8 + 1], x2 = z[n * 8 + 2];
        float x3 = z[n * 8 + 3], x4 = z[n * 8 + 4], x5 = z[n * 8 + 5];
        float s  = z[n * 8 + 6];
        float acc = fmaf(s, rvc, bc);
        acc = fmaf(x0, w0, acc); acc = fmaf(x1, w1, acc); acc = fmaf(x2, w2, acc);
        acc = fmaf(x3, w3, acc); acc = fmaf(x4, w4, acc); acc = fmaf(x5, w5, acc);
        out[(size_t)n * HID + c] = f2bf(fmaxf(acc, 0.f));
    }
}

// ---------------- MFMA GEMM: [N,256](bf16) @ (WhiT+WloT) + rv -> bf16 ----------------
__global__ __launch_bounds__(256) void k_gemm_mfma(
    const u16* __restrict__ X, const u16* __restrict__ WhiT,
    const u16* __restrict__ WloT, const float* __restrict__ rv,
    u16* __restrict__ out) {
    const int tid = threadIdx.x;
    const int wv = tid >> 6;
    const int ln = tid & 63;
    const int row0 = blockIdx.x * 64;
    const int lr = ln & 15;
    const int lk = (ln >> 4) * 8;
    const int wcol0 = wv * 64;

    f32x4 acc[4][4] = {};
    for (int kk = 0; kk < HID; kk += 32) {
        bf16x8 a[4], bh[4], bl[4];
#pragma unroll
        for (int i = 0; i < 4; ++i) {
            int r = row0 + i * 16 + lr;
            if (r >= N_NODES) r = N_NODES - 1;
            a[i] = *reinterpret_cast<const bf16x8*>(&X[(size_t)r * HID + kk + lk]);
        }
#pragma unroll
        for (int c = 0; c < 4; ++c) {
            int col = wcol0 + c * 16 + lr;
            bh[c] = *reinterpret_cast<const bf16x8*>(&WhiT[(size_t)col * HID + kk + lk]);
            bl[c] = *reinterpret_cast<const bf16x8*>(&WloT[(size_t)col * HID + kk + lk]);
        }
#pragma unroll
        for (int i = 0; i < 4; ++i)
#pragma unroll
            for (int c = 0; c < 4; ++c) {
                acc[i][c] = __builtin_amdgcn_mfma_f32_16x16x32_bf16(a[i], bh[c], acc[i][c], 0, 0, 0);
                acc[i][c] = __builtin_amdgcn_mfma_f32_16x16x32_bf16(a[i], bl[c], acc[i][c], 0, 0, 0);
            }
    }
    const int crow = (ln >> 4) * 4;
#pragma unroll
    for (int c = 0; c < 4; ++c) {
        int col = wcol0 + c * 16 + lr;
        float rvc = rv[col];
#pragma unroll
        for (int i = 0; i < 4; ++i) {
#pragma unroll
            for (int rg = 0; rg < 4; ++rg) {
                int r = row0 + i * 16 + crow + rg;
                if (r < N_NODES)
                    out[(size_t)r * HID + col] = f2bf(acc[i][c][rg] + rvc);
            }
        }
    }
}

// ---------------- aggregation: y = relu(S.xw + bias) ----------------
__global__ __launch_bounds__(256) void k_agg(
    const u16* __restrict__ xw, const int* __restrict__ ptr,
    const int* __restrict__ esrc, const float* __restrict__ dinv,
    const float* __restrict__ bias, u16* __restrict__ y) {
    const int wv = threadIdx.x >> 6;
    const int ln = threadIdx.x & 63;
    const int n = blockIdx.x * 4 + wv;
    const float dn = dinv[n];
    const size_t base = (size_t)n * HID + ln * 4;
    float4 v = ld_bf16x4(&xw[base]);
    const float sl = dn * dn;
    float a0 = v.x * sl, a1 = v.y * sl, a2 = v.z * sl, a3 = v.w * sl;
    const int s = ptr[n], e = ptr[n + 1];
#pragma unroll 2
    for (int i = s; i < e; ++i) {
        int src = __builtin_nontemporal_load(&esrc[i]);
        float w = dinv[src] * dn;
        float4 u = ld_bf16x4(&xw[(size_t)src * HID + ln * 4]);
        a0 = fmaf(w, u.x, a0);
        a1 = fmaf(w, u.y, a1);
        a2 = fmaf(w, u.z, a2);
        a3 = fmaf(w, u.w, a3);
    }
    float4 b = *reinterpret_cast<const float4*>(&bias[ln * 4]);
    a0 = fmaxf(a0 + b.x, 0.f);
    a1 = fmaxf(a1 + b.y, 0.f);
    a2 = fmaxf(a2 + b.z, 0.f);
    a3 = fmaxf(a3 + b.w, 0.f);
    ushort4 o;
    o.x = f2bf(a0); o.y = f2bf(a1); o.z = f2bf(a2); o.w = f2bf(a3);
    *reinterpret_cast<ushort4*>(&y[base]) = o;
}

// ---------------- per-channel stats partials: contiguous chunks, PB blocks ------
__global__ __launch_bounds__(256) void k_stats(const u16* __restrict__ y,
                                               float* __restrict__ part /* PB*512 */) {
    const int c = threadIdx.x;
    const int n0 = blockIdx.x * SROWS;
    const int n1 = (n0 + SROWS < N_NODES) ? n0 + SROWS : N_NODES;
    float s = 0.f, q = 0.f;
    int n = n0;
    for (; n + 3 < n1; n += 4) {
        float v0 = bf2f(y[(size_t)n * HID + c]);
        float v1 = bf2f(y[(size_t)(n + 1) * HID + c]);
        float v2 = bf2f(y[(size_t)(n + 2) * HID + c]);
        float v3 = bf2f(y[(size_t)(n + 3) * HID + c]);
        s += v0 + v1 + v2 + v3;
        q = fmaf(v0, v0, q); q = fmaf(v1, v1, q);
        q = fmaf(v2, v2, q); q = fmaf(v3, v3, q);
    }
    for (; n < n1; ++n) {
        float v = bf2f(y[(size_t)n * HID + c]);
        s += v;
        q = fmaf(v, v, q);
    }
    part[blockIdx.x * 512 + c] = s;
    part[blockIdx.x * 512 + HID + c] = q;
}

// ---------------- pooled sums by graph (batch is sorted) ----------------
__global__ __launch_bounds__(256) void k_pool(
    const u16* __restrict__ y, const int* __restrict__ batch,
    float* __restrict__ ps) {
    const int c = threadIdx.x;
    int r0 = blockIdx.x * 64;
    if (r0 >= N_NODES) return;
    int rend = (r0 + 64 < N_NODES) ? r0 + 64 : N_NODES;
    int cur = batch[r0];
    float acc = 0.f;
    for (int r = r0; r < rend; ++r) {
        int g = batch[r];
        if (g != cur) {
            atomicAdd(&ps[cur * HID + c], acc);
            acc = 0.f;
            cur = g;
        }
        acc += bf2f(y[(size_t)r * HID + c]);
    }
    atomicAdd(&ps[cur * HID + c], acc);
}

// ---------------- finalize: BN4 affine on pooled sums (reduces partials) ----------------
__global__ void k_final(const float* __restrict__ ps, const int* __restrict__ cg,
                        const float* __restrict__ part, const float* __restrict__ gamma,
                        const float* __restrict__ beta, float* __restrict__ out) {
    __shared__ float ss[HID], sq[HID];
    const int c = threadIdx.x;
    {
        float a = 0.f, b = 0.f;
#pragma unroll 4
        for (int bb = 0; bb < PB; ++bb) {
            a += part[bb * 512 + c];
            b += part[bb * 512 + HID + c];
        }
        ss[c] = a; sq[c] = b;
    }
    __syncthreads();
    const float invn = 1.0f / (float)N_NODES;
    float m = ss[c] * invn;
    float var = sq[c] * invn - m * m;
    float A = gamma[c] * rsqrtf(var + BN_EPS);
    float B = beta[c] - m * A;
    for (int g = 0; g < NG; ++g) {
        float cn = (float)cg[g];
        float val = (A * ps[g * HID + c] + cn * B) / fmaxf(cn, 1.0f);
        out[g * HID + c] = val;
    }
}

extern "C" void kernel_launch(void* const* d_in, const int* in_sizes, int n_in,
                              void* d_out, int out_size, void* d_ws, size_t ws_size,
                              hipStream_t stream) {
    const float* pos   = (const float*)d_in[0];
    const float* nrm   = (const float*)d_in[1];
    const int*   ei    = (const int*)d_in[2];
    const int*   batch = (const int*)d_in[3];
    const float* bn0g  = (const float*)d_in[4];
    const float* bn0b  = (const float*)d_in[5];
    const float* W[4]   = {(const float*)d_in[6],  (const float*)d_in[10], (const float*)d_in[14], (const float*)d_in[18]};
    const float* bb[4]  = {(const float*)d_in[7],  (const float*)d_in[11], (const float*)d_in[15], (const float*)d_in[19]};
    const float* bg[4]  = {(const float*)d_in[8],  (const float*)d_in[12], (const float*)d_in[16], (const float*)d_in[20]};
    const float* bbt[4] = {(const float*)d_in[9],  (const float*)d_in[13], (const float*)d_in[17], (const float*)d_in[21]};

    char* wp = (char*)d_ws;
    auto alloc = [&](size_t bytes) {
        char* p = wp;
        wp += (bytes + 255) & ~(size_t)255;
        return p;
    };
    float* dinv  = (float*)alloc((size_t)N_NODES * 4);
    int*   cnt   = (int*)  alloc((size_t)N_NODES * 4);
    int*   ptr   = (int*)  alloc((size_t)(N_NODES + 1) * 4);
    int*   esrc  = (int*)  alloc((size_t)N_EDGES * 4);
    u16*   bufA  = (u16*)  alloc((size_t)N_NODES * HID * 2);
    u16*   bufB  = (u16*)  alloc((size_t)N_NODES * HID * 2);
    float* zbuf  = (float*)alloc((size_t)N_NODES * 8 * 4);
    float* part0 = (float*)alloc((size_t)B0 * 12 * 4);
    float* partL = (float*)alloc((size_t)PB * 512 * 4);
    float* Wf1   = (float*)alloc((size_t)6 * HID * 4);
    u16*   WhiT  = (u16*)  alloc((size_t)HID * HID * 2);
    u16*   WloT  = (u16*)  alloc((size_t)HID * HID * 2);
    float* rv    = (float*)alloc(HID * 4);
    float* ps    = (float*)alloc(NG * HID * 4);
    int*   cg    = (int*)  alloc(NG * 4);
    (void)ws_size; (void)in_sizes; (void)n_in; (void)out_size;

    const int* rowi = ei;
    const int* coli = ei + N_EDGES;

    hipMemsetAsync(cnt, 0, (size_t)N_NODES * 4, stream);
    hipMemsetAsync(ps, 0, NG * HID * 4, stream);
    hipMemsetAsync(cg, 0, NG * 4, stream);

    // CSR + norms
    k_count<<<2048, 256, 0, stream>>>(coli, cnt);
    k_dinv<<<(N_NODES + 255) / 256, 256, 0, stream>>>(cnt, dinv);
    k_scan<<<1, 1024, 0, stream>>>(cnt, ptr);
    hipMemsetAsync(cnt, 0, (size_t)N_NODES * 4, stream);
    k_fill<<<2048, 256, 0, stream>>>(rowi, coli, ptr, cnt, esrc);
    k_batchcnt<<<(N_NODES + 255) / 256, 256, 0, stream>>>(batch, cg);

    // layer 1: aggregate in 6-dim raw space, then tiny GEMM with BN0 folded
    k_bn0stats<<<B0, 256, 0, stream>>>(pos, nrm, part0);
    k_fold6<<<1, 256, 0, stream>>>(W[0], part0, 1.0f / (float)N_NODES, bn0g, bn0b, Wf1, rv);
    k_agg6<<<N_NODES / 4, 256, 0, stream>>>(pos, nrm, ptr, esrc, dinv, zbuf);
    k_gemm1b<<<2048, 256, 0, stream>>>(zbuf, Wf1, rv, bb[0], bufA);   // bufA = a_1

    // layers 2..4: stats -> fold BN_l into W_{l+1} -> MFMA gemm -> aggregate
    for (int l = 0; l < 3; ++l) {
        k_stats<<<PB, 256, 0, stream>>>(bufA, partL);
        k_fold256<<<1, 256, 0, stream>>>(W[l + 1], partL, 1.0f / (float)N_NODES,
                                         bg[l], bbt[l], WhiT, WloT, rv);
        k_gemm_mfma<<<(N_NODES + 63) / 64, 256, 0, stream>>>(bufA, WhiT, WloT, rv, bufB);
        k_agg<<<N_NODES / 4, 256, 0, stream>>>(bufB, ptr, esrc, dinv, bb[l + 1], bufA);
    }

    // final BN4 applied analytically on pooled sums
    k_stats<<<PB, 256, 0, stream>>>(bufA, partL);
    k_pool<<<(N_NODES + 63) / 64, 256, 0, stream>>>(bufA, batch, ps);
    k_final<<<1, 256, 0, stream>>>(ps, cg, partL, bg[3], bbt[3], (float*)d_out);
}

// Round 8
// 1894.128 us; speedup vs baseline: 1.6075x; 1.1293x over previous
//
#include <hip/hip_runtime.h>
#include <hip/hip_bf16.h>
#include <cstdint>

#define N_NODES 100000
#define N_EDGES 3200000
#define HID 256
#define NG 16
#define BN_EPS 1e-5f
#define B0 120       // bn0stats partial blocks
#define PB 1024      // stats partial blocks
#define SROWS ((N_NODES + PB - 1) / PB)   // 98 rows per stats block
#define PBR 128      // second-stage reduction blocks
#define RPR (PB / PBR)                    // 8 partial rows per reduce block

typedef unsigned short u16;
using bf16x8 = __attribute__((ext_vector_type(8))) short;
using f32x4  = __attribute__((ext_vector_type(4))) float;

__device__ __forceinline__ float bf2f(u16 b) {
    return __uint_as_float(((unsigned)b) << 16);
}
__device__ __forceinline__ u16 f2bf(float f) {
    unsigned u = __float_as_uint(f);
    unsigned r = (u + 0x7FFFu + ((u >> 16) & 1u)) >> 16;
    return (u16)r;
}
__device__ __forceinline__ float4 ld_bf16x4(const u16* p) {
    ushort4 u = *reinterpret_cast<const ushort4*>(p);
    float4 f;
    f.x = bf2f(u.x); f.y = bf2f(u.y); f.z = bf2f(u.z); f.w = bf2f(u.w);
    return f;
}

// ---------------- CSR build ----------------
__global__ void k_count(const int* __restrict__ coli, int* __restrict__ cnt) {
    int i = blockIdx.x * blockDim.x + threadIdx.x;
    int st = gridDim.x * blockDim.x;
    for (; i < N_EDGES; i += st) atomicAdd(&cnt[coli[i]], 1);
}

// 1024-thread single-block scan (wave-shuffle) + fused dinv computation
__global__ void k_scan(const int* __restrict__ cnt, int* __restrict__ ptr,
                       float* __restrict__ dinv) {
    __shared__ int wsum[16];
    const int t = threadIdx.x;
    const int wv = t >> 6;
    const int ln = t & 63;
    int carry = 0;
    for (int base = 0; base < N_NODES; base += 4096) {
        int idx = base + t * 4;
        int v0 = 0, v1 = 0, v2 = 0, v3 = 0;
        if (idx + 3 < N_NODES) {
            int4 q = *reinterpret_cast<const int4*>(&cnt[idx]);
            v0 = q.x; v1 = q.y; v2 = q.z; v3 = q.w;
        } else {
            if (idx + 0 < N_NODES) v0 = cnt[idx + 0];
            if (idx + 1 < N_NODES) v1 = cnt[idx + 1];
            if (idx + 2 < N_NODES) v2 = cnt[idx + 2];
        }
        if (idx + 0 < N_NODES) dinv[idx + 0] = rsqrtf((float)v0 + 1.0f);
        if (idx + 1 < N_NODES) dinv[idx + 1] = rsqrtf((float)v1 + 1.0f);
        if (idx + 2 < N_NODES) dinv[idx + 2] = rsqrtf((float)v2 + 1.0f);
        if (idx + 3 < N_NODES) dinv[idx + 3] = rsqrtf((float)v3 + 1.0f);
        int s = v0 + v1 + v2 + v3;
        int sc = s;
        for (int off = 1; off < 64; off <<= 1) {
            int u = __shfl_up(sc, off);
            if (ln >= off) sc += u;
        }
        if (ln == 63) wsum[wv] = sc;
        __syncthreads();
        if (wv == 0 && ln < 16) {
            int a = wsum[ln];
            for (int off = 1; off < 16; off <<= 1) {
                int u = __shfl_up(a, off, 16);
                if (ln >= off) a += u;
            }
            wsum[ln] = a;
        }
        __syncthreads();
        int total = wsum[15];
        int excl = carry + (wv ? wsum[wv - 1] : 0) + sc - s;
        if (idx + 0 < N_NODES) ptr[idx + 0] = excl; excl += v0;
        if (idx + 1 < N_NODES) ptr[idx + 1] = excl; excl += v1;
        if (idx + 2 < N_NODES) ptr[idx + 2] = excl; excl += v2;
        if (idx + 3 < N_NODES) ptr[idx + 3] = excl;
        __syncthreads();
        carry += total;
    }
    if (t == 0) ptr[N_NODES] = carry;
}

// fill via atomic bump on a copy of ptr (no second memset, no separate ptr read)
__global__ void k_fill(const int* __restrict__ rowi, const int* __restrict__ coli,
                       int* __restrict__ ptr2, int* __restrict__ esrc) {
    int i = blockIdx.x * blockDim.x + threadIdx.x;
    int st = gridDim.x * blockDim.x;
    for (; i < N_EDGES; i += st) {
        int c = coli[i];
        int r = rowi[i];
        int p = atomicAdd(&ptr2[c], 1);
        esrc[p] = r;
    }
}

// per-block LDS histogram -> 16 global atomics per block
__global__ __launch_bounds__(256) void k_batchcnt(const int* __restrict__ batch,
                                                  int* __restrict__ cg) {
    __shared__ int h[NG];
    if (threadIdx.x < NG) h[threadIdx.x] = 0;
    __syncthreads();
    int i = blockIdx.x * blockDim.x + threadIdx.x;
    if (i < N_NODES) atomicAdd(&h[batch[i]], 1);
    __syncthreads();
    if (threadIdx.x < NG) {
        int v = h[threadIdx.x];
        if (v) atomicAdd(&cg[threadIdx.x], v);
    }
}

// ---------------- BN0 stats: block-reduced partials ----------------
__global__ __launch_bounds__(256) void k_bn0stats(const float* __restrict__ pos,
                                                  const float* __restrict__ nrm,
                                                  float* __restrict__ part /* B0*12 */) {
    float s[6] = {0, 0, 0, 0, 0, 0}, q[6] = {0, 0, 0, 0, 0, 0};
    int i = blockIdx.x * blockDim.x + threadIdx.x;
    int stp = gridDim.x * blockDim.x;
    for (; i < N_NODES; i += stp) {
        float v;
        v = pos[i * 3 + 0]; s[0] += v; q[0] += v * v;
        v = pos[i * 3 + 1]; s[1] += v; q[1] += v * v;
        v = pos[i * 3 + 2]; s[2] += v; q[2] += v * v;
        v = nrm[i * 3 + 0]; s[3] += v; q[3] += v * v;
        v = nrm[i * 3 + 1]; s[4] += v; q[4] += v * v;
        v = nrm[i * 3 + 2]; s[5] += v; q[5] += v * v;
    }
#pragma unroll
    for (int k = 0; k < 6; ++k) {
        for (int o = 32; o > 0; o >>= 1) { s[k] += __shfl_down(s[k], o); q[k] += __shfl_down(q[k], o); }
    }
    __shared__ float ls[4][12];
    const int wv = threadIdx.x >> 6;
    const int ln = threadIdx.x & 63;
    if (ln == 0) {
#pragma unroll
        for (int k = 0; k < 6; ++k) { ls[wv][k] = s[k]; ls[wv][6 + k] = q[k]; }
    }
    __syncthreads();
    if (threadIdx.x < 12)
        part[blockIdx.x * 12 + threadIdx.x] =
            ls[0][threadIdx.x] + ls[1][threadIdx.x] + ls[2][threadIdx.x] + ls[3][threadIdx.x];
}

// ---------------- fold BN0 into W1 (K=6): Wf=A*W, rvB = B^T W ----------------
__global__ void k_fold6(const float* __restrict__ W,
                        const float* __restrict__ part, float invcnt,
                        const float* __restrict__ gamma, const float* __restrict__ beta,
                        float* __restrict__ Wf, float* __restrict__ rvB) {
    __shared__ float st[12];
    int c = threadIdx.x;
    if (c < 12) {
        float a = 0.f;
        for (int b = 0; b < B0; ++b) a += part[b * 12 + c];
        st[c] = a;
    }
    __syncthreads();
    float acc = 0.f;
    for (int k = 0; k < 6; ++k) {
        float m = st[k] * invcnt;
        float var = st[6 + k] * invcnt - m * m;
        float A = gamma[k] * rsqrtf(var + BN_EPS);
        float B = beta[k] - m * A;
        float w = W[k * HID + c];
        Wf[k * HID + c] = A * w;
        acc = fmaf(B, w, acc);
    }
    rvB[c] = acc;
}

// ---------------- second-stage reduction of stats partials: PB -> PBR rows ------
__global__ __launch_bounds__(256) void k_reduce(const float* __restrict__ part,
                                                float* __restrict__ red) {
    const int b = blockIdx.x;
    const int t = threadIdx.x;
    float a0 = 0.f, a1 = 0.f;
#pragma unroll
    for (int r = 0; r < RPR; ++r) {
        const float* p = &part[(size_t)(b * RPR + r) * 512];
        a0 += p[t];
        a1 += p[t + 256];
    }
    red[(size_t)b * 512 + t] = a0;
    red[(size_t)b * 512 + 256 + t] = a1;
}

// ---------------- fold for K=256 (reduces PBR reduced partials in preamble) -----
__global__ void k_fold256(const float* __restrict__ W,
                          const float* __restrict__ red /* PBR*512 */, float invcnt,
                          const float* __restrict__ gamma, const float* __restrict__ beta,
                          u16* __restrict__ WhiT, u16* __restrict__ WloT,
                          float* __restrict__ rv) {
    __shared__ float ss[HID], sq[HID];
    int c = threadIdx.x;
    {
        float a = 0.f, b = 0.f;
#pragma unroll 4
        for (int bb = 0; bb < PBR; ++bb) {
            a += red[bb * 512 + c];
            b += red[bb * 512 + HID + c];
        }
        ss[c] = a; sq[c] = b;
    }
    __syncthreads();
    float acc = 0.f;
    for (int k = 0; k < HID; ++k) {
        float m = ss[k] * invcnt;
        float var = sq[k] * invcnt - m * m;
        float A = gamma[k] * rsqrtf(var + BN_EPS);
        float B = beta[k] - m * A;
        float w = W[k * HID + c];
        float wf = A * w;
        u16 hi = f2bf(wf);
        WhiT[c * HID + k] = hi;
        WloT[c * HID + k] = f2bf(wf - bf2f(hi));
        acc = fmaf(B, w, acc);
    }
    rv[c] = acc;
}

// ---------------- layer-1 pre-aggregation in 6-dim raw space ----------------
__global__ __launch_bounds__(256) void k_agg6(
    const float* __restrict__ pos, const float* __restrict__ nrm,
    const int* __restrict__ ptr, const int* __restrict__ esrc,
    const float* __restrict__ dinv, float* __restrict__ z) {
    const int wv = threadIdx.x >> 6;
    const int ln = threadIdx.x & 63;
    const int n = blockIdx.x * 4 + wv;
    const float dn = dinv[n];
    float z0 = 0, z1 = 0, z2 = 0, z3 = 0, z4 = 0, z5 = 0, t = 0;
    const int s_ = ptr[n], e_ = ptr[n + 1];
    for (int e = s_ + ln; e < e_; e += 64) {
        int src = esrc[e];
        float w = dn * dinv[src];
        z0 = fmaf(w, pos[src * 3 + 0], z0);
        z1 = fmaf(w, pos[src * 3 + 1], z1);
        z2 = fmaf(w, pos[src * 3 + 2], z2);
        z3 = fmaf(w, nrm[src * 3 + 0], z3);
        z4 = fmaf(w, nrm[src * 3 + 1], z4);
        z5 = fmaf(w, nrm[src * 3 + 2], z5);
        t += w;
    }
    if (ln == 0) {   // self loop
        float sl = dn * dn;
        z0 = fmaf(sl, pos[n * 3 + 0], z0);
        z1 = fmaf(sl, pos[n * 3 + 1], z1);
        z2 = fmaf(sl, pos[n * 3 + 2], z2);
        z3 = fmaf(sl, nrm[n * 3 + 0], z3);
        z4 = fmaf(sl, nrm[n * 3 + 1], z4);
        z5 = fmaf(sl, nrm[n * 3 + 2], z5);
        t += sl;
    }
#pragma unroll
    for (int o = 1; o < 64; o <<= 1) {
        z0 += __shfl_xor(z0, o); z1 += __shfl_xor(z1, o); z2 += __shfl_xor(z2, o);
        z3 += __shfl_xor(z3, o); z4 += __shfl_xor(z4, o); z5 += __shfl_xor(z5, o);
        t  += __shfl_xor(t, o);
    }
    if (ln == 0) {
        *reinterpret_cast<f32x4*>(&z[n * 8])     = f32x4{z0, z1, z2, z3};
        *reinterpret_cast<f32x4*>(&z[n * 8 + 4]) = f32x4{z4, z5, t, 0.f};
    }
}

// ---------------- layer-1: y1 = relu(z6 @ Wf + s*rvB + b1) -> bf16 ----------------
__global__ __launch_bounds__(256) void k_gemm1b(
    const float* __restrict__ z, const float* __restrict__ Wf,
    const float* __restrict__ rvB, const float* __restrict__ b1,
    u16* __restrict__ out) {
    const int c = threadIdx.x;
    float w0 = Wf[0 * HID + c], w1 = Wf[1 * HID + c], w2 = Wf[2 * HID + c];
    float w3 = Wf[3 * HID + c], w4 = Wf[4 * HID + c], w5 = Wf[5 * HID + c];
    const float rvc = rvB[c], bc = b1[c];
    for (int n = blockIdx.x; n < N_NODES; n += gridDim.x) {
        float x0 = z[n * 8 + 0], x1 = z[n * 8 + 1], x2 = z[n * 8 + 2];
        float x3 = z[n * 8 + 3], x4 = z[n * 8 + 4], x5 = z[n * 8 + 5];
        float s  = z[n * 8 + 6];
        float acc = fmaf(s, rvc, bc);
        acc = fmaf(x0, w0, acc); acc = fmaf(x1, w1, acc); acc = fmaf(x2, w2, acc);
        acc = fmaf(x3, w3, acc); acc = fmaf(x4, w4, acc); acc = fmaf(x5, w5, acc);
        out[(size_t)n * HID + c] = f2bf(fmaxf(acc, 0.f));
    }
}

// ---------------- MFMA GEMM: [N,256](bf16) @ (WhiT+WloT) + rv -> bf16 ----------------
__global__ __launch_bounds__(256) void k_gemm_mfma(
    const u16* __restrict__ X, const u16* __restrict__ WhiT,
    const u16* __restrict__ WloT, const float* __restrict__ rv,
    u16* __restrict__ out) {
    const int tid = threadIdx.x;
    const int wv = tid >> 6;
    const int ln = tid & 63;
    const int row0 = blockIdx.x * 64;
    const int lr = ln & 15;
    const int lk = (ln >> 4) * 8;
    const int wcol0 = wv * 64;

    f32x4 acc[4][4] = {};
    for (int kk = 0; kk < HID; kk += 32) {
        bf16x8 a[4], bh[4], bl[4];
#pragma unroll
        for (int i = 0; i < 4; ++i) {
            int r = row0 + i * 16 + lr;
            if (r >= N_NODES) r = N_NODES - 1;
            a[i] = *reinterpret_cast<const bf16x8*>(&X[(size_t)r * HID + kk + lk]);
        }
#pragma unroll
        for (int c = 0; c < 4; ++c) {
            int col = wcol0 + c * 16 + lr;
            bh[c] = *reinterpret_cast<const bf16x8*>(&WhiT[(size_t)col * HID + kk + lk]);
            bl[c] = *reinterpret_cast<const bf16x8*>(&WloT[(size_t)col * HID + kk + lk]);
        }
#pragma unroll
        for (int i = 0; i < 4; ++i)
#pragma unroll
            for (int c = 0; c < 4; ++c) {
                acc[i][c] = __builtin_amdgcn_mfma_f32_16x16x32_bf16(a[i], bh[c], acc[i][c], 0, 0, 0);
                acc[i][c] = __builtin_amdgcn_mfma_f32_16x16x32_bf16(a[i], bl[c], acc[i][c], 0, 0, 0);
            }
    }
    const int crow = (ln >> 4) * 4;
#pragma unroll
    for (int c = 0; c < 4; ++c) {
        int col = wcol0 + c * 16 + lr;
        float rvc = rv[col];
#pragma unroll
        for (int i = 0; i < 4; ++i) {
#pragma unroll
            for (int rg = 0; rg < 4; ++rg) {
                int r = row0 + i * 16 + crow + rg;
                if (r < N_NODES)
                    out[(size_t)r * HID + col] = f2bf(acc[i][c][rg] + rvc);
            }
        }
    }
}

// ---------------- aggregation: y = relu(S.xw + bias) ----------------
__global__ __launch_bounds__(256) void k_agg(
    const u16* __restrict__ xw, const int* __restrict__ ptr,
    const int* __restrict__ esrc, const float* __restrict__ dinv,
    const float* __restrict__ bias, u16* __restrict__ y) {
    const int wv = threadIdx.x >> 6;
    const int ln = threadIdx.x & 63;
    const int n = blockIdx.x * 4 + wv;
    const float dn = dinv[n];
    const size_t base = (size_t)n * HID + ln * 4;
    float4 v = ld_bf16x4(&xw[base]);
    const float sl = dn * dn;
    float a0 = v.x * sl, a1 = v.y * sl, a2 = v.z * sl, a3 = v.w * sl;
    const int s = ptr[n], e = ptr[n + 1];
#pragma unroll 2
    for (int i = s; i < e; ++i) {
        int src = esrc[i];
        float w = dinv[src] * dn;
        float4 u = ld_bf16x4(&xw[(size_t)src * HID + ln * 4]);
        a0 = fmaf(w, u.x, a0);
        a1 = fmaf(w, u.y, a1);
        a2 = fmaf(w, u.z, a2);
        a3 = fmaf(w, u.w, a3);
    }
    float4 b = *reinterpret_cast<const float4*>(&bias[ln * 4]);
    a0 = fmaxf(a0 + b.x, 0.f);
    a1 = fmaxf(a1 + b.y, 0.f);
    a2 = fmaxf(a2 + b.z, 0.f);
    a3 = fmaxf(a3 + b.w, 0.f);
    ushort4 o;
    o.x = f2bf(a0); o.y = f2bf(a1); o.z = f2bf(a2); o.w = f2bf(a3);
    *reinterpret_cast<ushort4*>(&y[base]) = o;
}

// ---------------- per-channel stats partials: contiguous chunks, PB blocks ------
__global__ __launch_bounds__(256) void k_stats(const u16* __restrict__ y,
                                               float* __restrict__ part /* PB*512 */) {
    const int c = threadIdx.x;
    const int n0 = blockIdx.x * SROWS;
    const int n1 = (n0 + SROWS < N_NODES) ? n0 + SROWS : N_NODES;
    float s = 0.f, q = 0.f;
    int n = n0;
    for (; n + 3 < n1; n += 4) {
        float v0 = bf2f(y[(size_t)n * HID + c]);
        float v1 = bf2f(y[(size_t)(n + 1) * HID + c]);
        float v2 = bf2f(y[(size_t)(n + 2) * HID + c]);
        float v3 = bf2f(y[(size_t)(n + 3) * HID + c]);
        s += v0 + v1 + v2 + v3;
        q = fmaf(v0, v0, q); q = fmaf(v1, v1, q);
        q = fmaf(v2, v2, q); q = fmaf(v3, v3, q);
    }
    for (; n < n1; ++n) {
        float v = bf2f(y[(size_t)n * HID + c]);
        s += v;
        q = fmaf(v, v, q);
    }
    part[blockIdx.x * 512 + c] = s;
    part[blockIdx.x * 512 + HID + c] = q;
}

// ---------------- stats + pooled sums fused (batch sorted) ----------------
__global__ __launch_bounds__(256) void k_statspool(const u16* __restrict__ y,
                                                   const int* __restrict__ batch,
                                                   float* __restrict__ part,
                                                   float* __restrict__ ps) {
    const int c = threadIdx.x;
    const int n0 = blockIdx.x * SROWS;
    const int n1 = (n0 + SROWS < N_NODES) ? n0 + SROWS : N_NODES;
    float s = 0.f, q = 0.f;
    if (n0 < N_NODES) {
        int cur = batch[n0];
        float acc = 0.f;
        for (int n = n0; n < n1; ++n) {
            float v = bf2f(y[(size_t)n * HID + c]);
            int g = batch[n];
            if (g != cur) {
                atomicAdd(&ps[cur * HID + c], acc);
                acc = 0.f;
                cur = g;
            }
            s += v;
            q = fmaf(v, v, q);
            acc += v;
        }
        atomicAdd(&ps[cur * HID + c], acc);
    }
    part[blockIdx.x * 512 + c] = s;
    part[blockIdx.x * 512 + HID + c] = q;
}

// ---------------- finalize: BN4 affine on pooled sums (reduces PBR partials) ----
__global__ void k_final(const float* __restrict__ ps, const int* __restrict__ cg,
                        const float* __restrict__ red, const float* __restrict__ gamma,
                        const float* __restrict__ beta, float* __restrict__ out) {
    __shared__ float ss[HID], sq[HID];
    const int c = threadIdx.x;
    {
        float a = 0.f, b = 0.f;
#pragma unroll 4
        for (int bb = 0; bb < PBR; ++bb) {
            a += red[bb * 512 + c];
            b += red[bb * 512 + HID + c];
        }
        ss[c] = a; sq[c] = b;
    }
    __syncthreads();
    const float invn = 1.0f / (float)N_NODES;
    float m = ss[c] * invn;
    float var = sq[c] * invn - m * m;
    float A = gamma[c] * rsqrtf(var + BN_EPS);
    float B = beta[c] - m * A;
    for (int g = 0; g < NG; ++g) {
        float cn = (float)cg[g];
        float val = (A * ps[g * HID + c] + cn * B) / fmaxf(cn, 1.0f);
        out[g * HID + c] = val;
    }
}

extern "C" void kernel_launch(void* const* d_in, const int* in_sizes, int n_in,
                              void* d_out, int out_size, void* d_ws, size_t ws_size,
                              hipStream_t stream) {
    const float* pos   = (const float*)d_in[0];
    const float* nrm   = (const float*)d_in[1];
    const int*   ei    = (const int*)d_in[2];
    const int*   batch = (const int*)d_in[3];
    const float* bn0g  = (const float*)d_in[4];
    const float* bn0b  = (const float*)d_in[5];
    const float* W[4]   = {(const float*)d_in[6],  (const float*)d_in[10], (const float*)d_in[14], (const float*)d_in[18]};
    const float* bb[4]  = {(const float*)d_in[7],  (const float*)d_in[11], (const float*)d_in[15], (const float*)d_in[19]};
    const float* bg[4]  = {(const float*)d_in[8],  (const float*)d_in[12], (const float*)d_in[16], (const float*)d_in[20]};
    const float* bbt[4] = {(const float*)d_in[9],  (const float*)d_in[13], (const float*)d_in[17], (const float*)d_in[21]};

    char* wp = (char*)d_ws;
    auto alloc = [&](size_t bytes) {
        char* p = wp;
        wp += (bytes + 255) & ~(size_t)255;
        return p;
    };
    float* dinv  = (float*)alloc((size_t)N_NODES * 4);
    int*   cnt   = (int*)  alloc((size_t)N_NODES * 4);
    int*   ptr   = (int*)  alloc((size_t)(N_NODES + 1) * 4);
    int*   ptr2  = (int*)  alloc((size_t)N_NODES * 4);
    int*   esrc  = (int*)  alloc((size_t)N_EDGES * 4);
    u16*   bufA  = (u16*)  alloc((size_t)N_NODES * HID * 2);
    u16*   bufB  = (u16*)  alloc((size_t)N_NODES * HID * 2);
    float* zbuf  = (float*)alloc((size_t)N_NODES * 8 * 4);
    float* part0 = (float*)alloc((size_t)B0 * 12 * 4);
    float* partL = (float*)alloc((size_t)PB * 512 * 4);
    float* red   = (float*)alloc((size_t)PBR * 512 * 4);
    float* Wf1   = (float*)alloc((size_t)6 * HID * 4);
    u16*   WhiT  = (u16*)  alloc((size_t)HID * HID * 2);
    u16*   WloT  = (u16*)  alloc((size_t)HID * HID * 2);
    float* rv    = (float*)alloc(HID * 4);
    float* ps    = (float*)alloc(NG * HID * 4);
    int*   cg    = (int*)  alloc(NG * 4);
    (void)ws_size; (void)in_sizes; (void)n_in; (void)out_size;

    const int* rowi = ei;
    const int* coli = ei + N_EDGES;

    hipMemsetAsync(cnt, 0, (size_t)N_NODES * 4, stream);
    hipMemsetAsync(ps, 0, NG * HID * 4, stream);
    hipMemsetAsync(cg, 0, NG * 4, stream);

    // CSR + norms
    k_count<<<2048, 256, 0, stream>>>(coli, cnt);
    k_scan<<<1, 1024, 0, stream>>>(cnt, ptr, dinv);
    hipMemcpyAsync(ptr2, ptr, (size_t)N_NODES * 4, hipMemcpyDeviceToDevice, stream);
    k_fill<<<2048, 256, 0, stream>>>(rowi, coli, ptr2, esrc);
    k_batchcnt<<<(N_NODES + 255) / 256, 256, 0, stream>>>(batch, cg);

    // layer 1: aggregate in 6-dim raw space, then tiny GEMM with BN0 folded
    k_bn0stats<<<B0, 256, 0, stream>>>(pos, nrm, part0);
    k_fold6<<<1, 256, 0, stream>>>(W[0], part0, 1.0f / (float)N_NODES, bn0g, bn0b, Wf1, rv);
    k_agg6<<<N_NODES / 4, 256, 0, stream>>>(pos, nrm, ptr, esrc, dinv, zbuf);
    k_gemm1b<<<2048, 256, 0, stream>>>(zbuf, Wf1, rv, bb[0], bufA);   // bufA = a_1

    // layers 2..4: stats -> reduce -> fold BN_l into W_{l+1} -> MFMA gemm -> aggregate
    for (int l = 0; l < 3; ++l) {
        k_stats<<<PB, 256, 0, stream>>>(bufA, partL);
        k_reduce<<<PBR, 256, 0, stream>>>(partL, red);
        k_fold256<<<1, 256, 0, stream>>>(W[l + 1], red, 1.0f / (float)N_NODES,
                                         bg[l], bbt[l], WhiT, WloT, rv);
        k_gemm_mfma<<<(N_NODES + 63) / 64, 256, 0, stream>>>(bufA, WhiT, WloT, rv, bufB);
        k_agg<<<N_NODES / 4, 256, 0, stream>>>(bufB, ptr, esrc, dinv, bb[l + 1], bufA);
    }

    // final: fused stats+pool, then BN4 applied analytically on pooled sums
    k_statspool<<<PB, 256, 0, stream>>>(bufA, batch, partL, ps);
    k_reduce<<<PBR, 256, 0, stream>>>(partL, red);
    k_final<<<1, 256, 0, stream>>>(ps, cg, red, bg[3], bbt[3], (float*)d_out);
}